// Round 1
// 372.334 us; speedup vs baseline: 1.0506x; 1.0506x over previous
//
#include <hip/hip_runtime.h>
#include <math.h>

// Fused two-head classifier via bf16 MFMA GEMM:
//   C[65536 x 48] = embs[65536 x 1024] (bf16-cast) x B[1024 x 48]
//   B cols 0..4 = W_status, 5..34 = W_flight, 35..47 = zero pad.
//   Epilogue: dual softmax + gating, done with 16-lane shuffle butterflies
//   (C/D layout: col = lane&15, row = (lane>>4)*4 + reg).
//
// Per wave: 16 rows, full K=1024 (32 k-steps x 3 mfma_f32_16x16x32_bf16).
// A fragments loaded straight from global (lane = row n=lane&15,
// k-chunk (lane>>4)*8) with next-step prefetch; each row's 128B line region
// is fully consumed per k-step -> embs read exactly once (268 MB).
// B staged per K-half into 48 KB LDS in fragment order -> stride-1
// ds_read_b128, no scalar loads in the hot loop.
//
// NEW (this round): k-phase rotation to break stride-4096 HBM channel
// aliasing. A-loads at a given k-step hit 16 rows at exactly 4 KiB stride
// (all addresses congruent mod 4 KiB); wave distance (64 KiB) and block
// distance (1 MiB) are both congruent 0 mod the channel-interleave period,
// and all 256 blocks run in lock-step -> the whole GPU hammers a small
// rotating subset of HBM channels at any instant. Since MFMA accumulation
// is order-independent, each wave consumes its k-steps in a rotated cyclic
// order: half order rotated per block (blockIdx&1), 16 steps within a half
// rotated by (wv + 3*blockIdx)&15 per wave. B is fully staged per half
// before the loop, so any within-half order is legal; the A prefetch chain
// follows the rotated sequence (with a cross-half prefetch at the boundary).

typedef __bf16 bf16x8 __attribute__((ext_vector_type(8)));
typedef float  f32x4  __attribute__((ext_vector_type(4)));

#define ROWS_PER_BLOCK 256   // 16 waves * 16 rows
#define KSTEPS   32          // 1024 / 32
#define HALF_KS  16

__global__ __launch_bounds__(1024, 4)
void fused_heads_kernel(const float* __restrict__ embs,
                        const float* __restrict__ W_status,
                        const float* __restrict__ b_status,
                        const float* __restrict__ W_flight,
                        const float* __restrict__ b_flight,
                        float* __restrict__ out) {
    // B half-tile: [16 ks][3 frag][64 lanes] x 16B = 48 KB
    __shared__ bf16x8 Bsh[HALF_KS * 3 * 64];

    const int tid  = threadIdx.x;
    const int lane = tid & 63;
    const int wv   = tid >> 6;          // 0..15
    const int n    = lane & 15;         // MFMA row (A) / col (C)
    const int q    = lane >> 4;         // quad group 0..3

    const int rowbase = blockIdx.x * ROWS_PER_BLOCK + wv * 16;
    const float* aptr = embs + (size_t)(rowbase + n) * 1024 + q * 8;

    // --- k-phase decorrelation ---
    const int roffs = (wv + (int)blockIdx.x * 3) & 15;  // per-wave rotation in half
    const int h0    = (int)blockIdx.x & 1;              // per-block half order

    f32x4 acc0 = {0.f, 0.f, 0.f, 0.f};
    f32x4 acc1 = {0.f, 0.f, 0.f, 0.f};
    f32x4 acc2 = {0.f, 0.f, 0.f, 0.f};

    // prefetch A for the first (rotated) k-step
    const int ks0 = h0 * HALF_KS + roffs;
    float4 ca0 = *(const float4*)(aptr + ks0 * 32);
    float4 ca1 = *(const float4*)(aptr + ks0 * 32 + 4);

    for (int ph = 0; ph < 2; ++ph) {
        const int h = h0 ^ ph;          // actual K-half being processed
        __syncthreads();   // previous half's Bsh reads finished

        // ---- stage B half h (3072 frags, 3 per thread), coalesced LDS writes ----
#pragma unroll
        for (int i = 0; i < 3; ++i) {
            const int d   = tid + i * 1024;
            const int L   = d & 63;
            const int ksf = d >> 6;                    // 0..47 = ksl*3 + f
            const int ksl = ksf / 3;
            const int f   = ksf - ksl * 3;
            const int bn  = f * 16 + (L & 15);         // B column 0..47
            const int bk  = (h * HALF_KS + ksl) * 32 + (L >> 4) * 8;
            bf16x8 w;
#pragma unroll
            for (int j = 0; j < 8; ++j) w[j] = (__bf16)0.0f;
            if (bn < 35) {
                const float* src = (bn < 5) ? (W_status + bn * 1024 + bk)
                                            : (W_flight + (bn - 5) * 1024 + bk);
                const float4 w0 = *(const float4*)(src);
                const float4 w1 = *(const float4*)(src + 4);
                w[0] = (__bf16)w0.x; w[1] = (__bf16)w0.y;
                w[2] = (__bf16)w0.z; w[3] = (__bf16)w0.w;
                w[4] = (__bf16)w1.x; w[5] = (__bf16)w1.y;
                w[6] = (__bf16)w1.z; w[7] = (__bf16)w1.w;
            }
            Bsh[d] = w;
        }
        __syncthreads();   // Bsh half visible

        // ---- 16 rotated K-steps: prefetch A(next), cvt, 3x ds_read_b128, 3x MFMA ----
#pragma unroll 4
        for (int kl = 0; kl < HALF_KS; ++kl) {
            const int ksl = (kl + roffs) & 15;         // rotated step within half
            int nks;                                   // next global k-step (wave-uniform)
            if (kl < HALF_KS - 1)  nks = h * HALF_KS + ((kl + 1 + roffs) & 15);
            else if (ph == 0)      nks = (h0 ^ 1) * HALF_KS + roffs;  // first step of next half
            else                   nks = h * HALF_KS + ksl;           // clamp, no OOB
            const float4 na0 = *(const float4*)(aptr + nks * 32);
            const float4 na1 = *(const float4*)(aptr + nks * 32 + 4);

            bf16x8 af;
            af[0] = (__bf16)ca0.x; af[1] = (__bf16)ca0.y;
            af[2] = (__bf16)ca0.z; af[3] = (__bf16)ca0.w;
            af[4] = (__bf16)ca1.x; af[5] = (__bf16)ca1.y;
            af[6] = (__bf16)ca1.z; af[7] = (__bf16)ca1.w;

            const bf16x8 b0 = Bsh[(ksl * 3 + 0) * 64 + lane];
            const bf16x8 b1 = Bsh[(ksl * 3 + 1) * 64 + lane];
            const bf16x8 b2 = Bsh[(ksl * 3 + 2) * 64 + lane];

            acc0 = __builtin_amdgcn_mfma_f32_16x16x32_bf16(af, b0, acc0, 0, 0, 0);
            acc1 = __builtin_amdgcn_mfma_f32_16x16x32_bf16(af, b1, acc1, 0, 0, 0);
            acc2 = __builtin_amdgcn_mfma_f32_16x16x32_bf16(af, b2, acc2, 0, 0, 0);

            ca0 = na0; ca1 = na1;
        }
    }

    // ---- epilogue: per-row dual softmax across the 16-lane group ----
    // lane holds cols n, 16+n, 32+n for rows q*4+i (i = 0..3).
    const float bias0 = (n < 5) ? b_status[n] : b_flight[n - 5];
    const float bias1 = b_flight[n + 11];
    const float bias2 = (n < 3) ? b_flight[n + 27] : 0.0f;
    const int   gb    = lane & 48;   // group base lane

#pragma unroll
    for (int i = 0; i < 4; ++i) {
        const float v0 = acc0[i] + bias0;                       // col n
        const float v1 = acc1[i] + bias1;                       // col 16+n
        const float v2 = (n < 3) ? (acc2[i] + bias2) : -INFINITY; // col 32+n

        float ms = (n < 5) ? v0 : -INFINITY;                    // status max
        float mf = fmaxf((n >= 5) ? v0 : -INFINITY, fmaxf(v1, v2)); // flight max
#pragma unroll
        for (int m = 1; m < 16; m <<= 1) {
            ms = fmaxf(ms, __shfl_xor(ms, m));
            mf = fmaxf(mf, __shfl_xor(mf, m));
        }

        const float es  = (n < 5)  ? __expf(v0 - ms) : 0.0f;
        const float ef0 = (n >= 5) ? __expf(v0 - mf) : 0.0f;
        const float ef1 = __expf(v1 - mf);
        const float ef2 = (n < 3)  ? __expf(v2 - mf) : 0.0f;

        float ss = es;
        float sf = ef0 + ef1 + ef2;
#pragma unroll
        for (int m = 1; m < 16; m <<= 1) {
            ss += __shfl_xor(ss, m);
            sf += __shfl_xor(sf, m);
        }
        const float invs = 1.0f / ss;
        const float invf = 1.0f / sf;

        const float book   = __shfl(es, gb + 4) * invs * invf;  // s4 * invs * invf
        const float change = __shfl(es, gb + 3) * invs * invf;  // s3 * invs * invf

        float* orow = out + (size_t)(rowbase + q * 4 + i) * 63;
        if (n == 0) orow[0] = es * invs;            // no_flight  (status 0)
        if (n == 2) orow[1] = es * invs;            // cancel     (status 2)
        if (n == 1) orow[2] = es * invs;            // no_reservation (status 1)
        if (n >= 5) {                               // flight j = n-5  (cols 5..15)
            orow[3 + (n - 5)]  = book   * ef0;
            orow[33 + (n - 5)] = change * ef0;
        }
        orow[3 + (n + 11)]  = book   * ef1;         // flight j = n+11 (cols 16..31)
        orow[33 + (n + 11)] = change * ef1;
        if (n < 3) {                                // flight j = n+27 (cols 32..34)
            orow[3 + (n + 27)]  = book   * ef2;
            orow[33 + (n + 27)] = change * ef2;
        }
    }
}

extern "C" void kernel_launch(void* const* d_in, const int* in_sizes, int n_in,
                              void* d_out, int out_size, void* d_ws, size_t ws_size,
                              hipStream_t stream) {
    const float* embs     = (const float*)d_in[0];
    const float* W_status = (const float*)d_in[1];
    const float* b_status = (const float*)d_in[2];
    const float* W_flight = (const float*)d_in[3];
    const float* b_flight = (const float*)d_in[4];
    float* out = (float*)d_out;

    const int rows = in_sizes[0] / 1024;              // 65536
    const int grid = rows / ROWS_PER_BLOCK;           // 256

    fused_heads_kernel<<<grid, 1024, 0, stream>>>(
        embs, W_status, b_status, W_flight, b_flight, out);
}